// Round 5
// baseline (90.077 us; speedup 1.0000x reference)
//
#include <hip/hip_runtime.h>

#define L_LEN 4096
#define NT 1024
#define ROWS 512               // B*J = 32*16 fixed by the reference
#define SLOP 96u               // f32-key error band (fast-log/div error <= ~8 ulps; 12x margin)
#define BCAP 256
#define NW (NT / 64)           // 16 waves

// Round 15: 2 rows per block, software-pipelined (grid 512 -> 256, 1 block/CU).
// Row 1's w/u float4 loads are issued at kernel start, so their HBM latency
// hides under row 0's entire radix middle; both rows' ids load together so
// row 1's ids stream under row 0's band/output phases. Per-row phase body is
// byte-identical to round 14 (best, 86.56). All row-crossing LDS hazards are
// removed structurally: hist/h2/bkey/bidx/s_bn/s_cntw are [2]-indexed by the
// compile-time row slot, so no re-zeros and no inter-row barriers are needed.
// NOT reapplied (round-9/10 cliff): hist+logf fusion, cnt-from-hist.
// Round-13 lesson: never add a second dispatch (~6 us tax).

#define ROW_PHASE(R, AV, BV, IDA)                                                        \
{                                                                                        \
    float wv[4], uv[4];                                                                  \
    wv[0]=AV.x; wv[1]=AV.y; wv[2]=AV.z; wv[3]=AV.w;                                      \
    uv[0]=BV.x; uv[1]=BV.y; uv[2]=BV.z; uv[3]=BV.w;                                      \
    unsigned key[4];                                                                     \
    unsigned localnz = 0;                                                                \
    _Pragma("unroll")                                                                    \
    for (int e = 0; e < 4; ++e) {                                                        \
        key[e] = 0u;                               /* w<=0 -> bottom, never selected */  \
        if (wv[e] > 0.0f) {                                                              \
            float t = -__logf(uv[e]);                                                    \
            float r = __fdividef(fmaxf(wv[e], 1e-30f), t);                               \
            key[e] = __float_as_uint(r);                                                 \
            localnz++;                                                                   \
        }                                                                                \
    }                                                                                    \
    {                                                                                    \
        unsigned v = localnz;                                                            \
        _Pragma("unroll")                                                                \
        for (int off = 32; off > 0; off >>= 1) v += __shfl_down(v, off, 64);             \
        if (R == 0) {                                                                    \
            unsigned long long bal = __ballot(odd != 0u);                                \
            if (lane == 0) { s_cntw[R][wid] = v; s_orw[wid] = (bal != 0ull) ? 1u : 0u; } \
        } else {                                                                         \
            if (lane == 0) s_cntw[R][wid] = v;                                           \
        }                                                                                \
    }                                                                                    \
    __syncthreads();                              /* covers zeroing + wave sums */       \
    unsigned cnt = 0;                                                                    \
    _Pragma("unroll")                                                                    \
    for (int w2 = 0; w2 < NW; ++w2) cnt += s_cntw[R][w2];                                \
    const int k = (int)floorf(0.15f * (float)cnt);  /* f32(0.15)*f32(cnt), floored */    \
    if (R == 0) {                                                                        \
        unsigned orr = 0;                                                                \
        _Pragma("unroll")                                                                \
        for (int w2 = 0; w2 < NW; ++w2) orr |= s_orw[w2];                                \
        is64 = (orr == 0u);                                                              \
        /* Prefetch BOTH rows' ids: row0's overlaps its radix passes, row1's */          \
        /* streams under row0's band + output phases. */                                 \
        if (!is64) {                                                                     \
            int4 t0 = reinterpret_cast<const int4*>(ids + (size_t)row0 * L_LEN)[tid];    \
            ida0[0]=t0.x; ida0[1]=t0.y; ida0[2]=t0.z; ida0[3]=t0.w;                      \
            int4 t1 = reinterpret_cast<const int4*>(ids + (size_t)(row0+1) * L_LEN)[tid];\
            ida1[0]=t1.x; ida1[1]=t1.y; ida1[2]=t1.z; ida1[3]=t1.w;                      \
        } else {                                                                         \
            const long long* idp = (const long long*)ids;                                \
            const longlong2* i0 = reinterpret_cast<const longlong2*>(                    \
                idp + (size_t)row0 * L_LEN);                                             \
            longlong2 a = i0[2 * tid], b = i0[2 * tid + 1];                              \
            ida0[0]=(int)a.x; ida0[1]=(int)a.y; ida0[2]=(int)b.x; ida0[3]=(int)b.y;      \
            const longlong2* i1 = reinterpret_cast<const longlong2*>(                    \
                idp + (size_t)(row0 + 1) * L_LEN);                                       \
            longlong2 c = i1[2 * tid], d = i1[2 * tid + 1];                              \
            ida1[0]=(int)c.x; ida1[1]=(int)c.y; ida1[2]=(int)d.x; ida1[3]=(int)d.y;      \
        }                                                                                \
    }                                                                                    \
    unsigned lo_thr = 0xFFFFFFFFu, hi_thr = 0xFFFFFFFFu;   /* k==0: select none */       \
    int need = 0;                                                                        \
    unsigned bn = 0;                                                                     \
    if (k > 0) {                                                                         \
        /* Pass 0: 12-bit field (bits 31:20), 4096 bins (pre-zeroed at top). */          \
        _Pragma("unroll")                                                                \
        for (int e = 0; e < 4; ++e) atomicAdd(&hist[R][key[e] >> 20], 1u);               \
        __syncthreads();                                                                 \
        {                                                                                \
            int b0i = 4095 - 4 * tid;              /* 4 descending bins per thread */    \
            unsigned c[4], lsum = 0;                                                     \
            _Pragma("unroll")                                                            \
            for (int m = 0; m < 4; ++m) { c[m] = hist[R][b0i - m]; lsum += c[m]; }       \
            unsigned scan = lsum;                                                        \
            _Pragma("unroll")                                                            \
            for (int off = 1; off < 64; off <<= 1) {                                     \
                unsigned o = __shfl_up(scan, (unsigned)off, 64);                         \
                if (lane >= off) scan += o;                                              \
            }                                                                            \
            if (lane == 63) s_wtot[wid] = scan;                                          \
            __syncthreads();                                                             \
            unsigned woff = 0;                     /* inline cross-wave prefix */        \
            _Pragma("unroll")                                                            \
            for (int w2 = 0; w2 < NW; ++w2) woff += (w2 < wid) ? s_wtot[w2] : 0u;        \
            unsigned run = woff + (scan - lsum);   /* count in strictly-higher bins */   \
            unsigned remk = (unsigned)k;                                                 \
            _Pragma("unroll")                                                            \
            for (int m = 0; m < 4; ++m) {                                                \
                if (run < remk && run + c[m] >= remk) {  /* exactly one hit */           \
                    s_prefix = (unsigned)(b0i - m);                                      \
                    s_remk = remk - run;                                                 \
                }                                                                        \
                run += c[m];                                                             \
            }                                                                            \
        }                                                                                \
        __syncthreads();                                                                 \
        unsigned prefix12 = s_prefix;                                                    \
        unsigned remk = s_remk;                                                          \
        /* Pass 1: 8-bit field (bits 19:12), 256 bins, matching keys only. */            \
        _Pragma("unroll")                                                                \
        for (int e = 0; e < 4; ++e)                                                      \
            if ((key[e] >> 20) == prefix12)                                              \
                atomicAdd(&h2[R][(key[e] >> 12) & 0xFFu], 1u);                           \
        __syncthreads();                                                                 \
        if (tid < 64) {                            /* wave 0: descending-bin scan */     \
            unsigned c[4], lsum = 0;                                                     \
            _Pragma("unroll")                                                            \
            for (int m = 0; m < 4; ++m) { c[m] = h2[R][255 - 4 * tid - m]; lsum += c[m]; }\
            unsigned scan = lsum;                                                        \
            _Pragma("unroll")                                                            \
            for (int off = 1; off < 64; off <<= 1) {                                     \
                unsigned o = __shfl_up(scan, (unsigned)off, 64);                         \
                if (tid >= off) scan += o;                                               \
            }                                                                            \
            unsigned run = scan - lsum;                                                  \
            _Pragma("unroll")                                                            \
            for (int m = 0; m < 4; ++m) {                                                \
                if (run < remk && run + c[m] >= remk) {                                  \
                    s_prefix = (prefix12 << 8) | (unsigned)(255 - 4 * tid - m);          \
                }                                                                        \
                run += c[m];                                                             \
            }                                                                            \
        }                                                                                \
        __syncthreads();                                                                 \
        const unsigned T20 = s_prefix;             /* k-th key's 20-bit prefix */        \
        const unsigned B_lo = T20 << 12, B_hi = (T20 << 12) | 0xFFFu;                    \
        /* Band: key > hi => certainly top-k; key < lo => certainly not; */              \
        /* band members resolved exactly in f64 below. */                                \
        lo_thr = (B_lo > SLOP) ? B_lo - SLOP : 1u; /* >=1 excludes w<=0 sentinels */     \
        hi_thr = B_hi + SLOP;                      /* no overflow (keys <= 0x7F800000) */\
        unsigned nhi = 0;                                                                \
        _Pragma("unroll")                                                                \
        for (int e = 0; e < 4; ++e) {                                                    \
            if (key[e] > hi_thr) {                                                       \
                nhi++;                                                                   \
            } else if (key[e] >= lo_thr) {                                               \
                unsigned pos = atomicAdd(&s_bn[R], 1u);                                  \
                if (pos < BCAP) {                                                        \
                    double t = -log((double)uv[e]);                                      \
                    double r = (double)fmaxf(wv[e], 1e-30f) / t;  /* exact-order key */  \
                    bkey[R][pos] = (unsigned long long)__double_as_longlong(r);          \
                    bidx[R][pos] = 4 * tid + e;                                          \
                }                                                                        \
            }                                                                            \
        }                                                                                \
        {                                                                                \
            unsigned nv = nhi;                                                           \
            _Pragma("unroll")                                                            \
            for (int off = 32; off > 0; off >>= 1) nv += __shfl_down(nv, off, 64);       \
            if (lane == 0) s_nhiw[wid] = nv;                                             \
        }                                                                                \
        __syncthreads();                                                                 \
        unsigned nhi_tot = 0;                                                            \
        _Pragma("unroll")                                                                \
        for (int w2 = 0; w2 < NW; ++w2) nhi_tot += s_nhiw[w2];                           \
        need = k - (int)nhi_tot;                   /* >= 1; bn >= need by construction */\
        bn = s_bn[R]; if (bn > BCAP) bn = BCAP;                                          \
    }                                                                                    \
    /* Phase 3: selection + float32 outputs for row (row0+R). */                         \
    const size_t obase = (size_t)(row0 + R) * L_LEN;                                     \
    float* o0 = out + obase;                                                             \
    float* o1 = out + (size_t)n_per + obase;                                             \
    float* o2 = out + 2 * (size_t)n_per + obase;                                         \
    float f0[4], f1[4], f2[4];                                                           \
    _Pragma("unroll")                                                                    \
    for (int e = 0; e < 4; ++e) {                                                        \
        bool sel;                                                                        \
        if (key[e] > hi_thr) {                                                           \
            sel = true;                                                                  \
        } else if (key[e] < lo_thr) {                                                    \
            sel = false;                                                                 \
        } else {                                                                         \
            /* band member: rank by (f64 key desc, index asc) — stable, exact */         \
            double t = -log((double)uv[e]);                                              \
            double r = (double)fmaxf(wv[e], 1e-30f) / t;                                 \
            unsigned long long myk = (unsigned long long)__double_as_longlong(r);        \
            int myi = 4 * tid + e;                                                       \
            int rnk = 0;                                                                 \
            for (unsigned j = 0; j < bn; ++j)                                            \
                rnk += (bkey[R][j] > myk) || (bkey[R][j] == myk && bidx[R][j] < myi);    \
            sel = (rnk < need);                                                          \
        }                                                                                \
        f0[e] = sel ? 103.0f : (float)IDA[e];                                            \
        f1[e] = sel ? 1.0f : 0.0f;                                                       \
        f2[e] = sel ? -1.0f : -0.0f;                                                     \
    }                                                                                    \
    reinterpret_cast<float4*>(o0)[tid] = make_float4(f0[0], f0[1], f0[2], f0[3]);        \
    reinterpret_cast<float4*>(o1)[tid] = make_float4(f1[0], f1[1], f1[2], f1[3]);        \
    reinterpret_cast<float4*>(o2)[tid] = make_float4(f2[0], f2[1], f2[2], f2[3]);        \
}

__global__ __launch_bounds__(NT, 4) void AttentionEssentialReinforce_51238959841470_kernel(
    const int* __restrict__ ids,       // int32 OR little-endian int64 (auto-detected)
    const float* __restrict__ amask,   // (ROWS, 2*L), only first half used
    const float* __restrict__ uin,     // (ROWS, L)
    float* __restrict__ out,           // float32: [ids | mask | -mask], n_per each
    int n_per)
{
    __shared__ unsigned int hist[2][4096];       // 32 KB (pass 0, one slab per row)
    __shared__ unsigned int h2[2][256];          // pass 1 bins, per row
    __shared__ unsigned int s_cntw[2][NW], s_orw[NW], s_nhiw[NW], s_wtot[NW];
    __shared__ unsigned long long bkey[2][BCAP]; // band: exact f64 keys, per row
    __shared__ int bidx[2][BCAP];                // band: element indices, per row
    __shared__ unsigned int s_remk, s_prefix, s_bn[2];

    const int tid = threadIdx.x;
    const int lane = tid & 63, wid = tid >> 6;
    const int row0 = 2 * blockIdx.x;

    const float* w0 = amask + (size_t)row0 * (2 * L_LEN);
    const float* w1 = amask + (size_t)(row0 + 1) * (2 * L_LEN);
    const float* u0 = uin + (size_t)row0 * L_LEN;
    const float* u1 = uin + (size_t)(row0 + 1) * L_LEN;

    // ---- Issue BOTH rows' hot loads up front: row1's latency hides under
    // row0's entire radix middle (the burst-stagger this kernel exists for).
    float4 av0 = reinterpret_cast<const float4*>(w0)[tid];
    float4 bv0 = reinterpret_cast<const float4*>(u0)[tid];
    float4 av1 = reinterpret_cast<const float4*>(w1)[tid];
    float4 bv1 = reinterpret_cast<const float4*>(u1)[tid];
    // int64-vs-int32 id detection: LE int64 ids (<2^31) have all-zero odd words.
    unsigned odd = ((const unsigned*)ids)[2 * tid + 1];

    // Zero all histograms while the loads are in flight (off the critical path).
    {
        unsigned* hf = &hist[0][0];
        #pragma unroll
        for (int b = 0; b < 8192 / NT; ++b) hf[tid + b * NT] = 0u;
    }
    if (tid < 256) { h2[0][tid] = 0u; h2[1][tid] = 0u; }
    if (tid == 0) { s_bn[0] = 0u; s_bn[1] = 0u; }

    bool is64 = false;
    int ida0[4], ida1[4];

    ROW_PHASE(0, av0, bv0, ida0)
    ROW_PHASE(1, av1, bv1, ida1)
}

extern "C" void kernel_launch(void* const* d_in, const int* in_sizes, int n_in,
                              void* d_out, int out_size, void* d_ws, size_t ws_size,
                              hipStream_t stream) {
    const int*   ids   = (const int*)d_in[0];     // (B,J,L) ids (int32/int64 auto-detect)
    const float* amask = (const float*)d_in[1];   // (B,J,2L) float32
    const float* uin   = (const float*)d_in[2];   // (B,J,L) float32
    float* out = (float*)d_out;                   // float32 x (3 * B*J*L)

    const int n_per = ROWS * L_LEN;               // 2,097,152 (hardcoded geometry)

    AttentionEssentialReinforce_51238959841470_kernel<<<dim3(ROWS / 2), dim3(NT), 0, stream>>>(
        ids, amask, uin, out, n_per);
}

// Round 7
// 84.614 us; speedup vs baseline: 1.0646x; 1.0646x over previous
//
#include <hip/hip_runtime.h>

#define L_LEN 4096
#define NT 1024
#define ROWS 512               // B*J = 32*16 fixed by the reference
#define SLOP 96u               // f32-key error band (fast-log/div error <= ~8 ulps; 12x margin)
#define BCAP 256
#define NW (NT / 64)           // 16 waves

typedef float f32x4 __attribute__((ext_vector_type(4)));   // native vector for nt-store

// Round 17: round-16 retry — __builtin_nontemporal_store needs a NATIVE clang
// vector type, not HIP's float4 class. Stores now go through f32x4
// (ext_vector_type(4), same 16-byte layout -> global_store_dwordx4 nt).
// Everything else byte-identical to round 14 (best, 86.56 us).
// Ledger: occupancy +0 | barrier-diet -1.1 | split +6.8 WORSE | fastmath -0.4
//         | 2-row pipe +3.5 WORSE. Dispatch overhead ~5-7 us (r13).
// NOT reapplied (round-9/10 cliff): hist+logf fusion, cnt-from-hist.
__global__ __launch_bounds__(NT, 8) void AttentionEssentialReinforce_51238959841470_kernel(
    const int* __restrict__ ids,       // int32 OR little-endian int64 (auto-detected)
    const float* __restrict__ amask,   // (ROWS, 2*L), only first half used
    const float* __restrict__ uin,     // (ROWS, L)
    float* __restrict__ out,           // float32: [ids | mask | -mask], n_per each
    int n_per)
{
    __shared__ unsigned int hist[4096];          // 16 KB (pass 0: 12-bit bins)
    __shared__ unsigned int h2[256];             // pass 1 bins (pre-zeroed early)
    __shared__ unsigned int s_cntw[NW], s_orw[NW], s_nhiw[NW], s_wtot[NW];
    __shared__ unsigned long long bkey[BCAP];    // band: exact f64 keys
    __shared__ int bidx[BCAP];                   // band: element indices
    __shared__ unsigned int s_remk, s_prefix, s_bn;

    const int row = blockIdx.x;
    const int tid = threadIdx.x;
    const int lane = tid & 63, wid = tid >> 6;
    const float* wrow = amask + (size_t)row * (2 * L_LEN);
    const float* urow = uin + (size_t)row * L_LEN;

    // ---- Issue the hot loads first; everything below overlaps their latency.
    float4 a0 = reinterpret_cast<const float4*>(wrow)[tid];
    float4 b0 = reinterpret_cast<const float4*>(urow)[tid];
    // int64-vs-int32 id detection: LE int64 ids (<2^31) have all-zero odd words.
    unsigned odd = ((const unsigned*)ids)[2 * tid + 1];

    // Zero histograms while the loads are in flight (off the critical path).
    #pragma unroll
    for (int b = 0; b < 4096 / NT; ++b) hist[tid + b * NT] = 0u;
    if (tid < 256) h2[tid] = 0u;
    if (tid == 0) s_bn = 0u;

    // ---- Phase 1: f32 keys in registers. r = max(w,1e-30)/(-ln u) is monotone-
    // equivalent to log(max(w,1e-30))+gumbel(u); positive-float IEEE bits are
    // order-isomorphic to value. Fast math here is safe: error <= ~8 ulps,
    // covered by the SLOP band; exactness restored in the f64 refine.
    float wv[4], uv[4];
    wv[0]=a0.x; wv[1]=a0.y; wv[2]=a0.z; wv[3]=a0.w;
    uv[0]=b0.x; uv[1]=b0.y; uv[2]=b0.z; uv[3]=b0.w;

    unsigned key[4];
    unsigned localnz = 0;
    #pragma unroll
    for (int e = 0; e < 4; ++e) {
        key[e] = 0u;                                  // w<=0 -> bottom, never selected
        if (wv[e] > 0.0f) {
            float t = -__logf(uv[e]);
            float r = __fdividef(fmaxf(wv[e], 1e-30f), t);
            key[e] = __float_as_uint(r);
            localnz++;
        }
    }
    {
        unsigned long long bal = __ballot(odd != 0u);
        unsigned v = localnz;
        #pragma unroll
        for (int off = 32; off > 0; off >>= 1) v += __shfl_down(v, off, 64);
        if (lane == 0) { s_cntw[wid] = v; s_orw[wid] = (bal != 0ull) ? 1u : 0u; }
    }
    __syncthreads();                                  // covers keys' wave sums + zeroing

    unsigned cnt = 0, orr = 0;
    #pragma unroll
    for (int w2 = 0; w2 < NW; ++w2) { cnt += s_cntw[w2]; orr |= s_orw[w2]; }
    const bool is64 = (orr == 0u);
    const int k = (int)floorf(0.15f * (float)cnt);    // f32(0.15)*f32(cnt), floored (as np)

    // Prefetch ids now: L2 latency overlaps the radix passes below.
    int ida[4];
    if (!is64) {
        int4 t0 = reinterpret_cast<const int4*>(ids + (size_t)row * L_LEN)[tid];
        ida[0]=t0.x; ida[1]=t0.y; ida[2]=t0.z; ida[3]=t0.w;
    } else {
        const longlong2* idr = reinterpret_cast<const longlong2*>(
            (const long long*)ids + (size_t)row * L_LEN);
        longlong2 a = idr[2 * tid], b = idr[2 * tid + 1];
        ida[0]=(int)a.x; ida[1]=(int)a.y; ida[2]=(int)b.x; ida[3]=(int)b.y;
    }

    unsigned lo_thr = 0xFFFFFFFFu, hi_thr = 0xFFFFFFFFu;   // k==0: select none
    int need = 0;
    unsigned bn = 0;

    if (k > 0) {
        // ---- Phase 2: localize the k-th largest f32 key to its 20-bit-prefix bin.
        // Pass 0: 12-bit field (bits 31:20), 4096 bins (pre-zeroed above).
        #pragma unroll
        for (int e = 0; e < 4; ++e) atomicAdd(&hist[key[e] >> 20], 1u);
        __syncthreads();
        {
            int b0i = 4095 - 4 * tid;                // 4 descending bins per thread
            unsigned c[4], lsum = 0;
            #pragma unroll
            for (int m = 0; m < 4; ++m) { c[m] = hist[b0i - m]; lsum += c[m]; }
            unsigned scan = lsum;
            #pragma unroll
            for (int off = 1; off < 64; off <<= 1) {
                unsigned o = __shfl_up(scan, (unsigned)off, 64);
                if (lane >= off) scan += o;
            }
            if (lane == 63) s_wtot[wid] = scan;
            __syncthreads();
            unsigned woff = 0;                       // inline cross-wave prefix (no barrier)
            #pragma unroll
            for (int w2 = 0; w2 < NW; ++w2) woff += (w2 < wid) ? s_wtot[w2] : 0u;
            unsigned run = woff + (scan - lsum);     // count in strictly-higher bins
            unsigned remk = (unsigned)k;
            #pragma unroll
            for (int m = 0; m < 4; ++m) {
                if (run < remk && run + c[m] >= remk) {   // exactly one (thread,m) hits
                    s_prefix = (unsigned)(b0i - m);
                    s_remk = remk - run;
                }
                run += c[m];
            }
        }
        __syncthreads();
        unsigned prefix12 = s_prefix;
        unsigned remk = s_remk;

        // Pass 1: 8-bit field (bits 19:12), 256 bins (h2, pre-zeroed), matching keys only.
        #pragma unroll
        for (int e = 0; e < 4; ++e)
            if ((key[e] >> 20) == prefix12)
                atomicAdd(&h2[(key[e] >> 12) & 0xFFu], 1u);
        __syncthreads();
        if (tid < 64) {                              // wave 0: descending-bin scan
            unsigned c[4], lsum = 0;
            #pragma unroll
            for (int m = 0; m < 4; ++m) { c[m] = h2[255 - 4 * tid - m]; lsum += c[m]; }
            unsigned scan = lsum;
            #pragma unroll
            for (int off = 1; off < 64; off <<= 1) {
                unsigned o = __shfl_up(scan, (unsigned)off, 64);
                if (tid >= off) scan += o;
            }
            unsigned run = scan - lsum;
            #pragma unroll
            for (int m = 0; m < 4; ++m) {
                if (run < remk && run + c[m] >= remk) {
                    s_prefix = (prefix12 << 8) | (unsigned)(255 - 4 * tid - m);
                }
                run += c[m];
            }
        }
        __syncthreads();
        const unsigned T20 = s_prefix;               // k-th key's 20-bit prefix
        const unsigned B_lo = T20 << 12, B_hi = (T20 << 12) | 0xFFFu;

        // ---- Error band: [B_lo - SLOP, B_hi + SLOP]. key > hi => certainly top-k;
        // key < lo => certainly not; band resolved exactly in f64 below.
        lo_thr = (B_lo > SLOP) ? B_lo - SLOP : 1u;   // >=1 excludes w<=0 sentinels
        hi_thr = B_hi + SLOP;                        // no overflow (keys <= 0x7F800000)
        unsigned nhi = 0;
        #pragma unroll
        for (int e = 0; e < 4; ++e) {
            if (key[e] > hi_thr) {
                nhi++;
            } else if (key[e] >= lo_thr) {
                unsigned pos = atomicAdd(&s_bn, 1u);
                if (pos < BCAP) {
                    double t = -log((double)uv[e]);
                    double r = (double)fmaxf(wv[e], 1e-30f) / t;   // exact-order key
                    bkey[pos] = (unsigned long long)__double_as_longlong(r);
                    bidx[pos] = 4 * tid + e;
                }
            }
        }
        {
            unsigned nv = nhi;
            #pragma unroll
            for (int off = 32; off > 0; off >>= 1) nv += __shfl_down(nv, off, 64);
            if (lane == 0) s_nhiw[wid] = nv;
        }
        __syncthreads();
        unsigned nhi_tot = 0;
        #pragma unroll
        for (int w2 = 0; w2 < NW; ++w2) nhi_tot += s_nhiw[w2];
        need = k - (int)nhi_tot;                     // >= 1; bn >= need by construction
        bn = s_bn; if (bn > BCAP) bn = BCAP;
    }

    // ---- Phase 3: selection + float32 outputs (non-temporal stores) ----
    const size_t obase = (size_t)row * L_LEN;
    float* o0 = out + obase;                      // masked ids
    float* o1 = out + (size_t)n_per + obase;      // mask
    float* o2 = out + 2 * (size_t)n_per + obase;  // -mask

    float f0[4], f1[4], f2[4];
    #pragma unroll
    for (int e = 0; e < 4; ++e) {
        bool sel;
        if (key[e] > hi_thr) {
            sel = true;
        } else if (key[e] < lo_thr) {
            sel = false;
        } else {
            // band member: rank by (f64 key desc, index asc) — stable, exact
            double t = -log((double)uv[e]);
            double r = (double)fmaxf(wv[e], 1e-30f) / t;
            unsigned long long myk = (unsigned long long)__double_as_longlong(r);
            int myi = 4 * tid + e;
            int rnk = 0;
            for (unsigned j = 0; j < bn; ++j)
                rnk += (bkey[j] > myk) || (bkey[j] == myk && bidx[j] < myi);
            sel = (rnk < need);
        }
        f0[e] = sel ? 103.0f : (float)ida[e];
        f1[e] = sel ? 1.0f : 0.0f;
        f2[e] = sel ? -1.0f : -0.0f;
    }
    // Write-once streams: nt stores (native f32x4 vectors) skip L2 allocation.
    {
        f32x4 v0 = { f0[0], f0[1], f0[2], f0[3] };
        f32x4 v1 = { f1[0], f1[1], f1[2], f1[3] };
        f32x4 v2 = { f2[0], f2[1], f2[2], f2[3] };
        __builtin_nontemporal_store(v0, &reinterpret_cast<f32x4*>(o0)[tid]);
        __builtin_nontemporal_store(v1, &reinterpret_cast<f32x4*>(o1)[tid]);
        __builtin_nontemporal_store(v2, &reinterpret_cast<f32x4*>(o2)[tid]);
    }
}

extern "C" void kernel_launch(void* const* d_in, const int* in_sizes, int n_in,
                              void* d_out, int out_size, void* d_ws, size_t ws_size,
                              hipStream_t stream) {
    const int*   ids   = (const int*)d_in[0];     // (B,J,L) ids (int32/int64 auto-detect)
    const float* amask = (const float*)d_in[1];   // (B,J,2L) float32
    const float* uin   = (const float*)d_in[2];   // (B,J,L) float32
    float* out = (float*)d_out;                   // float32 x (3 * B*J*L)

    const int n_per = ROWS * L_LEN;               // 2,097,152 (hardcoded geometry)

    AttentionEssentialReinforce_51238959841470_kernel<<<dim3(ROWS), dim3(NT), 0, stream>>>(
        ids, amask, uin, out, n_per);
}